// Round 6
// baseline (529.048 us; speedup 1.0000x reference)
//
#include <hip/hip_runtime.h>
#include <math.h>

typedef __attribute__((ext_vector_type(8))) short s16x8;
typedef __attribute__((ext_vector_type(4))) float f32x4;

#define MFMA(a, b, c) __builtin_amdgcn_mfma_f32_16x16x32_bf16(a, b, c, 0, 0, 0)

// ---- workspace layout (bytes) ----
#define KVF_OFF  0ull          // bf16 [h6][nt4][kk4][512]: nt0,1=K d=nt*16+l15, nt2,3=V d=(nt-2)*16+l15 (zeros d>=20,k>=120)
#define QF_OFF   98304ull      // bf16 [h6][nt2][kk4][512]: zeros nn>=20 or k>=120
#define PJF_OFF  147456ull     // bf16 [nt8][kk4][512]: zeros c>=120 or k>=120
#define RPB_OFF  180224ull     // f32  [h6][r64][n192]
#define KG_OFF   475136ull     // bf16 [w1024][tok192][144]: per-head stride 24 (d0..19 real, 20..23 zero)
#define QG_OFF   57098368ull   // bf16 [w1024][row64][192]: per-head stride 32 (zeros d>=20)
#define VT_OFF   82264192ull   // bf16 [w1024][120][192]: V^T rows h*20+d, cols tok
#define PRED_OFF 129458304ull  // f32  [w1024][64]

__device__ __forceinline__ unsigned short f2bf(float f) {
    union { float f; unsigned int i; } v; v.f = f;
    unsigned int x = v.i;
    x += 0x7fffu + ((x >> 16) & 1u);   // round-nearest-even
    return (unsigned short)(x >> 16);
}

// ---------------- prep: weight fragments + gathered rpb ----------------
__global__ void prep(const float* __restrict__ qkv_w,
                     const float* __restrict__ proj_w,
                     const float* __restrict__ rpb_table,
                     const int*   __restrict__ rel_idx,
                     unsigned char* __restrict__ wsb)
{
    int gid = blockIdx.x * blockDim.x + threadIdx.x;
    int nthr = gridDim.x * blockDim.x;
    unsigned short* KVF = (unsigned short*)(wsb + KVF_OFF);
    unsigned short* QF  = (unsigned short*)(wsb + QF_OFF);
    unsigned short* PJF = (unsigned short*)(wsb + PJF_OFF);
    float*          RPB = (float*)(wsb + RPB_OFF);

    // KVF: f = ((h*4+nt)*4+kk)*512 + ln*8 + j
    for (int f = gid; f < 6 * 4 * 4 * 512; f += nthr) {
        int q = f & 511, rest = f >> 9;
        int kk = rest & 3, rest2 = rest >> 2;
        int nt = rest2 & 3, h = rest2 >> 2;
        int ln = q >> 3, j = q & 7;
        int l15 = ln & 15, qd = ln >> 4;
        int k = kk * 32 + qd * 8 + j;
        float v = 0.f;
        if (k < 120) {
            if (nt < 2) { int d = nt * 16 + l15;       if (d < 20) v = qkv_w[(120 + h * 20 + d) * 120 + k]; }
            else        { int d = (nt - 2) * 16 + l15; if (d < 20) v = qkv_w[(240 + h * 20 + d) * 120 + k]; }
        }
        KVF[f] = f2bf(v);
    }
    // QF: f = ((h*2+nt)*4+kk)*512 + ln*8 + j
    for (int f = gid; f < 6 * 2 * 4 * 512; f += nthr) {
        int q = f & 511, rest = f >> 9;
        int kk = rest & 3, rest2 = rest >> 2;
        int nt = rest2 & 1, h = rest2 >> 1;
        int ln = q >> 3, j = q & 7;
        int l15 = ln & 15, qd = ln >> 4;
        int nn = nt * 16 + l15, k = kk * 32 + qd * 8 + j;
        float v = (k < 120 && nn < 20) ? qkv_w[(h * 20 + nn) * 120 + k] : 0.f;
        QF[f] = f2bf(v);
    }
    // PJF: f = (nt*4+kk)*512 + ln*8 + j
    for (int f = gid; f < 8 * 4 * 512; f += nthr) {
        int q = f & 511, rest = f >> 9;
        int kk = rest & 3, nt = rest >> 2;
        int ln = q >> 3, j = q & 7;
        int l15 = ln & 15, qd = ln >> 4;
        int c = nt * 16 + l15, k = kk * 32 + qd * 8 + j;
        float v = (k < 120 && c < 120) ? proj_w[c * 120 + k] : 0.f;
        PJF[f] = f2bf(v);
    }
    // RPB: [h][r][n]
    for (int i = gid; i < 6 * 64 * 192; i += nthr) {
        int n = i % 192, r = (i / 192) % 64, h = i / (192 * 64);
        RPB[i] = rpb_table[rel_idx[r * 192 + n] * 6 + h];
    }
}

// ---------------- K1: QKV projection -> MFMA-ready intermediates ----------------
__global__ __launch_bounds__(256, 3)
void k_qkv(const float* __restrict__ x, const float* __restrict__ quary0,
           const float* __restrict__ qkv_b, const float* __restrict__ pm_w,
           const float* __restrict__ pm_b, unsigned char* __restrict__ wsb)
{
    alignas(16) __shared__ unsigned short xw[192 * 120 + 16];
    const int tid = threadIdx.x;
    const int wv = tid >> 6, ln = tid & 63, l15 = ln & 15, qd = ln >> 4;
    const int widx = blockIdx.x, wh = widx >> 5, ww = widx & 31;
    const unsigned short* KVF = (const unsigned short*)(wsb + KVF_OFF);
    const unsigned short* QF  = (const unsigned short*)(wsb + QF_OFF);
    unsigned short* KG = (unsigned short*)(wsb + KG_OFF);
    unsigned short* QG = (unsigned short*)(wsb + QG_OFF);
    unsigned short* VT = (unsigned short*)(wsb + VT_OFF);
    float* PREDG = (float*)(wsb + PRED_OFF);

    // stage shifted window tokens (bf16)
    for (int e = tid; e < 192 * 30; e += 256) {
        int n = e / 30, c4 = e % 30;
        int f = n >> 6, ii = (n >> 3) & 7, jj = n & 7;
        int y0 = (wh * 8 + ii + 4) & 255;
        int x0 = (ww * 8 + jj + 4) & 255;
        float4 val = *(const float4*)(x + (((size_t)(f * 256 + y0)) * 256 + x0) * 120 + c4 * 4);
        unsigned int lo = (unsigned)f2bf(val.x) | ((unsigned)f2bf(val.y) << 16);
        unsigned int hi = (unsigned)f2bf(val.z) | ((unsigned)f2bf(val.w) << 16);
        unsigned int off = (unsigned)(n * 120 + c4 * 4);
        *(unsigned int*)(xw + off)     = lo;
        *(unsigned int*)(xw + off + 2) = hi;
    }
    // CRITICAL: zero the tail — token 191's A-fragment reads k=120..127 from here.
    // Uninitialized LDS can hold bf16 NaN/Inf patterns; NaN*0 = NaN in MFMA (R5 bug).
    if (tid < 16) xw[192 * 120 + tid] = 0;
    // pred in exact fp32 (sign-sensitive)
    {
        int r = tid >> 2, j = tid & 3;
        int ii = r >> 3, jj = r & 7;
        int y0 = (wh * 8 + ii + 4) & 255;
        int x0 = (ww * 8 + jj + 4) & 255;
        const float* xr  = x + (((size_t)(2 * 256 + y0)) * 256 + x0) * 120;
        const float* q0r = quary0 + ((size_t)widx * 64 + r) * 120;
        float acc = 0.f;
        for (int ch = j * 30; ch < j * 30 + 30; ++ch)
            acc += fabsf(xr[ch] - q0r[ch]) * pm_w[ch];
        acc += __shfl_xor(acc, 1);
        acc += __shfl_xor(acc, 2);
        if (j == 0) PREDG[widx * 64 + r] = (acc + pm_b[0] >= 0.f) ? 1.f : 0.f;
    }
    __syncthreads();

    const float SCALE = 0.22360679774997896f;   // 20^-0.5
    // 288 KV tiles + 48 q tiles over 4 waves
    for (int e = wv; e < 336; e += 4) {
        int mt, h, nt;
        const unsigned short *arow, *bb;
        bool isq = (e >= 288);
        if (!isq) {
            int ntg = e % 24; mt = e / 24; h = ntg >> 2; nt = ntg & 3;
            arow = xw + (mt * 16 + l15) * 120;
            bb = KVF + (size_t)((h * 4 + nt) * 4) * 512 + ln * 8;
        } else {
            int t = e - 288; int ntg = t % 12; mt = t / 12; h = ntg >> 1; nt = ntg & 1;
            arow = xw + (128 + mt * 16 + l15) * 120;
            bb = QF + (size_t)((h * 2 + nt) * 4) * 512 + ln * 8;
        }
        f32x4 acc = {0.f, 0.f, 0.f, 0.f};
        #pragma unroll
        for (int kk = 0; kk < 4; ++kk) {
            s16x8 aF = *(const s16x8*)(arow + kk * 32 + qd * 8);
            s16x8 bF = *(const s16x8*)(bb + kk * 512);
            acc = MFMA(aF, bF, acc);
        }
        if (!isq) {
            if (nt < 2) {                       // K -> KG[tok][h*24+d], d<24 (20..23 are zeros)
                int d = nt * 16 + l15;
                if (d < 24) {
                    float b = (d < 20) ? qkv_b[120 + h * 20 + d] : 0.f;
                    #pragma unroll
                    for (int reg = 0; reg < 4; ++reg) {
                        int tok = mt * 16 + qd * 4 + reg;
                        KG[((size_t)widx * 192 + tok) * 144 + h * 24 + d] = f2bf(acc[reg] + b);
                    }
                }
            } else {                            // V -> VT[h*20+d][tok]
                int d = (nt - 2) * 16 + l15;
                if (d < 20) {
                    float b = qkv_b[240 + h * 20 + d];
                    #pragma unroll
                    for (int reg = 0; reg < 4; ++reg) {
                        int tok = mt * 16 + qd * 4 + reg;
                        VT[((size_t)widx * 120 + h * 20 + d) * 192 + tok] = f2bf(acc[reg] + b);
                    }
                }
            }
        } else {                                // q -> QG[row][h*32+nn] (zeros nn>=20), scaled
            int nn = nt * 16 + l15;
            float b = (nn < 20) ? qkv_b[h * 20 + nn] : 0.f;
            #pragma unroll
            for (int reg = 0; reg < 4; ++reg) {
                int row = mt * 16 + qd * 4 + reg;
                float v = (nn < 20) ? (acc[reg] + b) * SCALE : 0.f;
                QG[((size_t)widx * 64 + row) * 192 + h * 32 + nn] = f2bf(v);
            }
        }
    }
}

// ---------------- K2: attention + proj + blend (wave = head, 1 barrier) ----------------
__global__ __launch_bounds__(384, 4)
void k_attn(const float* __restrict__ quary1, const float* __restrict__ proj_b,
            const unsigned char* __restrict__ wsb, float* __restrict__ out)
{
    alignas(16) __shared__ unsigned short ps[6 * 16 * 200];  // per-wave 16-row P slice
    alignas(16) __shared__ unsigned short os[64 * 136];      // attn out, cols 120..127 zero
    const int tid = threadIdx.x;
    const int h = tid >> 6, ln = tid & 63, l15 = ln & 15, qd = ln >> 4;
    const int widx = blockIdx.x, wh = widx >> 5, ww = widx & 31;

    const unsigned short* KG  = (const unsigned short*)(wsb + KG_OFF);
    const unsigned short* QG  = (const unsigned short*)(wsb + QG_OFF);
    const unsigned short* VT  = (const unsigned short*)(wsb + VT_OFF);
    const unsigned short* PJF = (const unsigned short*)(wsb + PJF_OFF);
    const float*          RPB = (const float*)(wsb + RPB_OFF);
    const float*        PREDG = (const float*)(wsb + PRED_OFF);

    for (int e = tid; e < 64 * 8; e += 384) os[(e >> 3) * 136 + 120 + (e & 7)] = 0;

    // shift-mask region ids on WINDOW coordinates (reference semantics!)
    int gk[12];
    #pragma unroll
    for (int t = 0; t < 12; ++t) {
        int p = (t * 16 + l15) & 63;
        int hg = (wh == 31) ? (1 + ((p >> 3) >= 4)) : 0;
        int wg = (ww == 31) ? (1 + ((p & 7) >= 4)) : 0;
        gk[t] = hg * 3 + wg;
    }

    unsigned short* psw = ps + h * 16 * 200;
    const unsigned short* kbase = KG + (size_t)widx * 192 * 144 + h * 24 + qd * 8;
    const unsigned short* vbase = VT + ((size_t)widx * 120 + h * 20) * 192 + qd * 8;

    for (int rt = 0; rt < 4; ++rt) {
        const int rb = rt * 16;
        // scores: S[row, tok], K=32 (q zeros at d>=20 kill K-side garbage)
        f32x4 sc[12];
        s16x8 qf = *(const s16x8*)(QG + ((size_t)widx * 64 + rb + l15) * 192 + h * 32 + qd * 8);
        #pragma unroll
        for (int t = 0; t < 12; ++t) {
            s16x8 bF = *(const s16x8*)(kbase + (size_t)(t * 16 + l15) * 144);
            f32x4 z = {0.f, 0.f, 0.f, 0.f};
            sc[t] = MFMA(qf, bF, z);
        }
        // softmax per row (rows rb + qd*4+reg, cols t*16+l15)
        #pragma unroll
        for (int reg = 0; reg < 4; ++reg) {
            int row = rb + qd * 4 + reg;
            int hgq = (wh == 31) ? (1 + ((row >> 3) >= 4)) : 0;
            int wgq = (ww == 31) ? (1 + ((row & 7) >= 4)) : 0;
            int gq = hgq * 3 + wgq;
            const float* rr = RPB + ((size_t)(h * 64 + row)) * 192;
            float m = -1e30f;
            #pragma unroll
            for (int t = 0; t < 12; ++t) {
                float v = sc[t][reg] + rr[t * 16 + l15] + ((gq == gk[t]) ? 0.f : -100.f);
                sc[t][reg] = v; m = fmaxf(m, v);
            }
            m = fmaxf(m, __shfl_xor(m, 1));
            m = fmaxf(m, __shfl_xor(m, 2));
            m = fmaxf(m, __shfl_xor(m, 4));
            m = fmaxf(m, __shfl_xor(m, 8));
            float s = 0.f;
            #pragma unroll
            for (int t = 0; t < 12; ++t) {
                float ev = __expf(sc[t][reg] - m);
                sc[t][reg] = ev; s += ev;
            }
            s += __shfl_xor(s, 1);
            s += __shfl_xor(s, 2);
            s += __shfl_xor(s, 4);
            s += __shfl_xor(s, 8);
            float inv = 1.0f / s;
            #pragma unroll
            for (int t = 0; t < 12; ++t)
                psw[(qd * 4 + reg) * 200 + t * 16 + l15] = f2bf(sc[t][reg] * inv);
        }
        // PV as O^T = V^T * P^T: A = VT rows (m=d), B = P rows (n=row), K=192
        f32x4 a0 = {0.f, 0.f, 0.f, 0.f}, a1 = {0.f, 0.f, 0.f, 0.f};
        #pragma unroll
        for (int kk = 0; kk < 6; ++kk) {
            s16x8 pF = *(const s16x8*)(psw + l15 * 200 + kk * 32 + qd * 8);
            s16x8 v0 = *(const s16x8*)(vbase + (size_t)l15 * 192 + kk * 32);
            s16x8 v1 = *(const s16x8*)(vbase + (size_t)(16 + l15) * 192 + kk * 32);
            a0 = MFMA(v0, pF, a0);
            a1 = MFMA(v1, pF, a1);
        }
        // C: m-row = d = qd*4+reg (+16), n-col = row = l15
        #pragma unroll
        for (int reg = 0; reg < 4; ++reg) {
            os[(rb + l15) * 136 + h * 20 + qd * 4 + reg] = f2bf(a0[reg]);
            if (qd == 0) os[(rb + l15) * 136 + h * 20 + 16 + reg] = f2bf(a1[reg]);
        }
    }
    __syncthreads();

    // proj GEMM (M=64, N=120 pad128, K=120 pad128) + blend + scatter
    for (int e = h; e < 32; e += 6) {
        int mt = e & 3, nt = e >> 2;
        int c = nt * 16 + l15;
        f32x4 acc = {0.f, 0.f, 0.f, 0.f};
        #pragma unroll
        for (int kk = 0; kk < 4; ++kk) {
            s16x8 aF = *(const s16x8*)(os + (mt * 16 + l15) * 136 + kk * 32 + qd * 8);
            s16x8 bF = *(const s16x8*)(PJF + (size_t)((nt * 4 + kk) * 512) + ln * 8);
            acc = MFMA(aF, bF, acc);
        }
        if (c < 120) {
            float pb = proj_b[c];
            #pragma unroll
            for (int reg = 0; reg < 4; ++reg) {
                int r = mt * 16 + qd * 4 + reg;
                float p = PREDG[widx * 64 + r];
                int ii = r >> 3, jj = r & 7;
                int y0 = (wh * 8 + ii + 4) & 255;
                int x0 = (ww * 8 + jj + 4) & 255;
                float fin = (p != 0.f) ? (acc[reg] + pb)
                                       : quary1[(size_t)widx * 7680 + (size_t)r * 120 + c];
                out[((size_t)(y0 * 256 + x0)) * 121 + c] = fin;
            }
        }
    }
    if (tid < 64) {
        int r = tid;
        int ii = r >> 3, jj = r & 7;
        int y0 = (wh * 8 + ii + 4) & 255;
        int x0 = (ww * 8 + jj + 4) & 255;
        out[((size_t)(y0 * 256 + x0)) * 121 + 120] = PREDG[widx * 64 + r];
    }
}

extern "C" void kernel_launch(void* const* d_in, const int* in_sizes, int n_in,
                              void* d_out, int out_size, void* d_ws, size_t ws_size,
                              hipStream_t stream) {
    const float* x        = (const float*)d_in[0];
    const float* quary0   = (const float*)d_in[1];
    const float* quary1   = (const float*)d_in[2];
    const float* qkv_w    = (const float*)d_in[3];
    const float* qkv_b    = (const float*)d_in[4];
    const float* proj_w   = (const float*)d_in[5];
    const float* proj_b   = (const float*)d_in[6];
    const float* rpb      = (const float*)d_in[7];
    const float* pm_w     = (const float*)d_in[8];
    const float* pm_b     = (const float*)d_in[9];
    const int*   rel_idx  = (const int*)d_in[11];
    float* out = (float*)d_out;
    unsigned char* wsb = (unsigned char*)d_ws;

    prep<<<256, 256, 0, stream>>>(qkv_w, proj_w, rpb, rel_idx, wsb);
    k_qkv<<<1024, 256, 0, stream>>>(x, quary0, qkv_b, pm_w, pm_b, wsb);
    k_attn<<<1024, 384, 0, stream>>>(quary1, proj_b, wsb, out);
}